// Round 1
// baseline (216.864 us; speedup 1.0000x reference)
//
#include <hip/hip_runtime.h>

// Problem constants (from reference)
#define BX 2
#define NX 128
#define NY 128
#define NZ 128
#define NC 4      // channels -> one float4 per voxel
#define ND 96     // output grid per spatial dim

constexpr int PPB   = ND * ND * ND;   // points per batch = 884736
constexpr int TOTAL = BX * PPB;       // 1769472

__device__ __forceinline__ float4 f4_lerp(float4 a, float4 b, float t) {
    // a*(1-t) + b*t, fused per component
    float4 r;
    r.x = fmaf(b.x - a.x, t, a.x);
    r.y = fmaf(b.y - a.y, t, a.y);
    r.z = fmaf(b.z - a.z, t, a.z);
    r.w = fmaf(b.w - a.w, t, a.w);
    return r;
}

__global__ __launch_bounds__(256) void ResamplerLayer_15668040696111_kernel(
    const float4* __restrict__ in,     // [B, X, Y, Z] voxels of float4 (C=4)
    const float*  __restrict__ coords, // [B, D, D, D, 3]
    float4*       __restrict__ out)    // [B, D, D, D] of float4
{
    int idx = blockIdx.x * blockDim.x + threadIdx.x;
    if (idx >= TOTAL) return;

    // coords for this point (12B/thread; wave reads contiguous 768B region)
    const float cx = coords[3 * idx + 0];
    const float cy = coords[3 * idx + 1];
    const float cz = coords[3 * idx + 2];

    const float fx = floorf(cx), fy = floorf(cy), fz = floorf(cz);
    const float wx = cx - fx, wy = cy - fy, wz = cz - fz;

    // REPLICATE boundary: clamp each corner index independently.
    // floor can be -1 .. size (coords in [-1, size]).
    int x0 = max(0, min((int)fx,     NX - 1));
    int x1 = max(0, min((int)fx + 1, NX - 1));
    int y0 = max(0, min((int)fy,     NY - 1));
    int y1 = max(0, min((int)fy + 1, NY - 1));
    int z0 = max(0, min((int)fz,     NZ - 1));
    int z1 = max(0, min((int)fz + 1, NZ - 1));

    const int b = idx / PPB;
    const float4* __restrict__ inb = in + (size_t)b * (NX * NY * NZ);

    // 8 corner gathers; z-pairs are contiguous (32B) -> good line utilization
    const float4* r00 = inb + ((size_t)x0 * NY + y0) * NZ;
    const float4* r01 = inb + ((size_t)x0 * NY + y1) * NZ;
    const float4* r10 = inb + ((size_t)x1 * NY + y0) * NZ;
    const float4* r11 = inb + ((size_t)x1 * NY + y1) * NZ;

    float4 v000 = r00[z0], v001 = r00[z1];
    float4 v010 = r01[z0], v011 = r01[z1];
    float4 v100 = r10[z0], v101 = r10[z1];
    float4 v110 = r11[z0], v111 = r11[z1];

    // lerp in z, then y, then x
    float4 c00 = f4_lerp(v000, v001, wz);
    float4 c01 = f4_lerp(v010, v011, wz);
    float4 c10 = f4_lerp(v100, v101, wz);
    float4 c11 = f4_lerp(v110, v111, wz);

    float4 c0 = f4_lerp(c00, c01, wy);
    float4 c1 = f4_lerp(c10, c11, wy);

    out[idx] = f4_lerp(c0, c1, wx);
}

extern "C" void kernel_launch(void* const* d_in, const int* in_sizes, int n_in,
                              void* d_out, int out_size, void* d_ws, size_t ws_size,
                              hipStream_t stream) {
    const float4* in     = (const float4*)d_in[0];   // inputs [2,128,128,128,4] f32
    const float*  coords = (const float*)d_in[1];    // sample_coords [2,96,96,96,3] f32
    float4*       out    = (float4*)d_out;           // [2,96,96,96,4] f32

    const int threads = 256;
    const int blocks  = (TOTAL + threads - 1) / threads;
    ResamplerLayer_15668040696111_kernel<<<blocks, threads, 0, stream>>>(in, coords, out);
}

// Round 4
// 195.384 us; speedup vs baseline: 1.1099x; 1.1099x over previous
//
#include <hip/hip_runtime.h>
#include <hip/hip_fp16.h>

// Problem constants (from reference)
#define BATCH 2
#define NS 128        // input spatial dim (X=Y=Z=128)
#define NB 64         // bricks per dim (2x2x2 voxel bricks)
#define ND 96         // output grid per spatial dim

constexpr int PPB   = ND * ND * ND;            // 884736 points per batch
constexpr int TOTAL = BATCH * PPB;             // 1769472
constexpr int BRICKS_PER_BATCH = NB * NB * NB; // 262144
constexpr int TOTAL_BRICKS = BATCH * BRICKS_PER_BATCH;
constexpr size_t WS_NEEDED = (size_t)TOTAL_BRICKS * 64; // 33.55 MB: fp16 bricks

__device__ __forceinline__ float4 f4_lerp(float4 a, float4 b, float t) {
    float4 r;
    r.x = fmaf(b.x - a.x, t, a.x);
    r.y = fmaf(b.y - a.y, t, a.y);
    r.z = fmaf(b.z - a.z, t, a.z);
    r.w = fmaf(b.w - a.w, t, a.w);
    return r;
}

// ---------------- Repack: fp32 linear -> fp16 2x2x2 bricks (64B/brick) ----
// One thread per 8-byte output chunk (= one voxel, 4 fp16).
// Chunk g: brick t = g>>3, local l = g&7 (lx,ly,lz); fully coalesced R/W.
__global__ __launch_bounds__(256) void repack_fp16_bricks(
    const float4* __restrict__ in, uint2* __restrict__ bricks)
{
    int g = blockIdx.x * 256 + threadIdx.x;   // grid sized exactly
    int t = g >> 3;
    int l = g & 7;
    int lx = (l >> 2) & 1, ly = (l >> 1) & 1, lz = l & 1;
    int b  = t >> 18;              // / 262144
    int r  = t & 262143;
    int x  = ((r >> 12) << 1) + lx;
    int y  = (((r >> 6) & 63) << 1) + ly;
    int z  = ((r & 63) << 1) + lz;

    float4 v = in[(((size_t)b * NS + x) * NS + y) * NS + z];
    __half2 h0 = __float22half2_rn(make_float2(v.x, v.y));
    __half2 h1 = __float22half2_rn(make_float2(v.z, v.w));
    uint2 p;
    p.x = *(const unsigned int*)&h0;
    p.y = *(const unsigned int*)&h1;
    bricks[g] = p;
}

__device__ __forceinline__ float4 vox_to_f4(uint2 v) {
    __half2 a = *(const __half2*)&v.x;
    __half2 b = *(const __half2*)&v.y;
    float2 f0 = __half22float2(a);
    float2 f1 = __half22float2(b);
    return make_float4(f0.x, f0.y, f1.x, f1.y);
}

// voxel (x,y,z) -> uint2 index into brick buffer (8B units)
__device__ __forceinline__ int brick_off(int x, int y, int z) {
    int bidx = (((x >> 1) * NB) + (y >> 1)) * NB + (z >> 1);
    return (bidx << 3) + ((x & 1) << 2) + ((y & 1) << 1) + (z & 1);
}

// ---------------- Resample from fp16 bricks --------------------------------
__global__ __launch_bounds__(256) void resample_bricks(
    const uint2* __restrict__ bricks,
    const float* __restrict__ coords,
    float4*      __restrict__ out)
{
    int idx = blockIdx.x * 256 + threadIdx.x;
    if (idx >= TOTAL) return;

    const float cx = coords[3 * idx + 0];
    const float cy = coords[3 * idx + 1];
    const float cz = coords[3 * idx + 2];

    const float fx = floorf(cx), fy = floorf(cy), fz = floorf(cz);
    const float wx = cx - fx, wy = cy - fy, wz = cz - fz;

    int x0 = max(0, min((int)fx,     NS - 1));
    int x1 = max(0, min((int)fx + 1, NS - 1));
    int y0 = max(0, min((int)fy,     NS - 1));
    int y1 = max(0, min((int)fy + 1, NS - 1));
    int z0 = max(0, min((int)fz,     NS - 1));
    int z1 = max(0, min((int)fz + 1, NS - 1));

    const uint2* __restrict__ wb =
        bricks + ((idx >= PPB) ? (size_t)BRICKS_PER_BATCH * 8 : 0);

    uint2 u000 = wb[brick_off(x0, y0, z0)];
    uint2 u001 = wb[brick_off(x0, y0, z1)];
    uint2 u010 = wb[brick_off(x0, y1, z0)];
    uint2 u011 = wb[brick_off(x0, y1, z1)];
    uint2 u100 = wb[brick_off(x1, y0, z0)];
    uint2 u101 = wb[brick_off(x1, y0, z1)];
    uint2 u110 = wb[brick_off(x1, y1, z0)];
    uint2 u111 = wb[brick_off(x1, y1, z1)];

    float4 c00 = f4_lerp(vox_to_f4(u000), vox_to_f4(u001), wz);
    float4 c01 = f4_lerp(vox_to_f4(u010), vox_to_f4(u011), wz);
    float4 c10 = f4_lerp(vox_to_f4(u100), vox_to_f4(u101), wz);
    float4 c11 = f4_lerp(vox_to_f4(u110), vox_to_f4(u111), wz);

    float4 c0 = f4_lerp(c00, c01, wy);
    float4 c1 = f4_lerp(c10, c11, wy);
    out[idx] = f4_lerp(c0, c1, wx);
}

// ---------------- Fallback: direct fp32 gather (if ws too small) -----------
__global__ __launch_bounds__(256) void resample_direct(
    const float4* __restrict__ in,
    const float*  __restrict__ coords,
    float4*       __restrict__ out)
{
    int idx = blockIdx.x * blockDim.x + threadIdx.x;
    if (idx >= TOTAL) return;

    const float cx = coords[3 * idx + 0];
    const float cy = coords[3 * idx + 1];
    const float cz = coords[3 * idx + 2];
    const float fx = floorf(cx), fy = floorf(cy), fz = floorf(cz);
    const float wx = cx - fx, wy = cy - fy, wz = cz - fz;

    int x0 = max(0, min((int)fx,     NS - 1));
    int x1 = max(0, min((int)fx + 1, NS - 1));
    int y0 = max(0, min((int)fy,     NS - 1));
    int y1 = max(0, min((int)fy + 1, NS - 1));
    int z0 = max(0, min((int)fz,     NS - 1));
    int z1 = max(0, min((int)fz + 1, NS - 1));

    const int b = idx / PPB;
    const float4* __restrict__ inb = in + (size_t)b * (NS * NS * NS);
    const float4* r00 = inb + ((size_t)x0 * NS + y0) * NS;
    const float4* r01 = inb + ((size_t)x0 * NS + y1) * NS;
    const float4* r10 = inb + ((size_t)x1 * NS + y0) * NS;
    const float4* r11 = inb + ((size_t)x1 * NS + y1) * NS;

    float4 c00 = f4_lerp(r00[z0], r00[z1], wz);
    float4 c01 = f4_lerp(r01[z0], r01[z1], wz);
    float4 c10 = f4_lerp(r10[z0], r10[z1], wz);
    float4 c11 = f4_lerp(r11[z0], r11[z1], wz);
    float4 c0 = f4_lerp(c00, c01, wy);
    float4 c1 = f4_lerp(c10, c11, wy);
    out[idx] = f4_lerp(c0, c1, wx);
}

extern "C" void kernel_launch(void* const* d_in, const int* in_sizes, int n_in,
                              void* d_out, int out_size, void* d_ws, size_t ws_size,
                              hipStream_t stream) {
    const float4* in     = (const float4*)d_in[0];
    const float*  coords = (const float*)d_in[1];
    float4*       out    = (float4*)d_out;

    if (ws_size >= WS_NEEDED) {
        uint2* bricks = (uint2*)d_ws;
        // repack: one thread per 8B chunk; TOTAL_BRICKS*8 threads
        int rp_threads = TOTAL_BRICKS * 8;                 // 4194304
        repack_fp16_bricks<<<rp_threads / 256, 256, 0, stream>>>(in, bricks);
        resample_bricks<<<(TOTAL + 255) / 256, 256, 0, stream>>>(bricks, coords, out);
    } else {
        resample_direct<<<(TOTAL + 255) / 256, 256, 0, stream>>>(in, coords, out);
    }
}